// Round 13
// baseline (23.744 us; speedup 1.0000x reference)
//
#include <hip/hip_runtime.h>

#define GX 512
#define NF 32
#define XD 1024
#define NPIX (XD * XD)

#define CELLB 64                 // f16 cell = 32 feats * 2 B
#define K1ROWB (32 * CELLB)      // kernel1 staged row: 32 cells, 2048 B

typedef _Float16 half8 __attribute__((ext_vector_type(8)));
typedef __fp16  fp16x2 __attribute__((ext_vector_type(2)));
typedef float  floatx4 __attribute__((ext_vector_type(4)));

union PkU { fp16x2 h; unsigned u; };
union FragU { half8 h; uint4 u4; fp16x2 p[4]; unsigned u[4]; };

__device__ __forceinline__ unsigned pkrtz(float a, float b) {
    PkU x; x.h = __builtin_amdgcn_cvt_pkrtz(a, b); return x.u;
}
__device__ __forceinline__ fp16x2 sp2(float w) {
    __fp16 h = (__fp16)w; fp16x2 v = {h, h}; return v;
}
__device__ __forceinline__ unsigned relu_pk(unsigned s) {
    unsigned r;
    asm("v_pk_max_f16 %0, %1, 0" : "=v"(r) : "v"(s));
    return r;
}
// G storage: G[(y*512+x)*4 + g] (uint4) = feats 8g..8g+7 of cell (y,x), f16.
__device__ __forceinline__ int g_idx16(int y, int x, int g) {
    return ((y << 9) + x) * 4 + g;
}

// ---- kernel 1: G[y][x] = W1^T * cell + b1 (f16, layer-1 folded) -------------
// Block = 4 grid rows x 32 cells. Staging + LDS swizzle/B-frag formulas are
// R11-verified verbatim. A-frag j-permutation J=8*(c>>2)+4*jt+(c&3) makes each
// lane's (d0,d1) = feats 8g..8g+7 -> one coalesced dwordx4 store per tile.
__global__ __launch_bounds__(256, 6) void t3d_gpass(
    const float* __restrict__ data,
    const float* __restrict__ W1, const float* __restrict__ b1,
    uint4* __restrict__ G)
{
    __shared__ uint4 lds4[(4 * K1ROWB) / 16];
    unsigned char* raw = (unsigned char*)lds4;

    const int tid  = threadIdx.x;
    const int wid  = tid >> 6;
    const int lane = tid & 63;
    const int c = lane & 15, g = lane >> 4;

    const int bid = blockIdx.x;
    const int wg  = (bid & 7) * 256 + (bid >> 3);   // same swizzle as kernel 2
    const int RB  = wg >> 4;          // grid rows 4RB..4RB+3
    const int cbk = wg & 15;          // cells 32cbk..32cbk+31
    const int XB  = 32 * cbk;
    const int YB  = 4 * RB;

    // staging: thread (cl, fl) loads cell cl's float4 #fl for each of 4 rows
    const int cl = tid >> 3, fl = tid & 7;
#pragma unroll
    for (int rr = 0; rr < 4; ++rr) {
        const floatx4* p = (const floatx4*)(data + ((size_t)(YB + rr) * GX + XB + cl) * NF + 4 * fl);
        const floatx4 v = __builtin_nontemporal_load(p);   // don't evict G from L2
        uint2 u = { pkrtz(v[0], v[1]), pkrtz(v[2], v[3]) };
        *(uint2*)(raw + rr * K1ROWB + cl * CELLB
                  + (((fl >> 1) ^ ((cl >> 1) & 3)) << 4) + ((fl & 1) << 3)) = u;
    }

    // A-frags with permuted j-mapping; bias b1[8g+4jt+r] as C-in
    FragU aw1[2]; floatx4 bia1[2];
    const int J = 8 * (c >> 2) + (c & 3);
#pragma unroll
    for (int jt = 0; jt < 2; ++jt) {
#pragma unroll
        for (int w = 0; w < 4; ++w)
            aw1[jt].u[w] = pkrtz(W1[(8*g + 2*w    ) * NF + J + 4*jt],
                                 W1[(8*g + 2*w + 1) * NF + J + 4*jt]);
        bia1[jt] = ((const floatx4*)b1)[2 * g + jt];
    }

    __syncthreads();

    // per-wave: grid row YB+wid, two 16-cell segments
#pragma unroll
    for (int seg = 0; seg < 2; ++seg) {
        const int cell = (seg << 4) + c;
        FragU B;
        B.u4 = *(const uint4*)(raw + wid * K1ROWB + cell * CELLB
                               + ((g ^ ((cell >> 1) & 3)) << 4));
        floatx4 d0 = __builtin_amdgcn_mfma_f32_16x16x32_f16(aw1[0].h, B.h, bia1[0], 0, 0, 0);
        floatx4 d1 = __builtin_amdgcn_mfma_f32_16x16x32_f16(aw1[1].h, B.h, bia1[1], 0, 0, 0);
        uint4 u = { pkrtz(d0[0], d0[1]), pkrtz(d0[2], d0[3]),
                    pkrtz(d1[0], d1[1]), pkrtz(d1[2], d1[3]) };   // feats 8g..8g+7
        G[g_idx16(YB + wid, XB + cell, g)] = u;
    }
}

// ---- kernel 2: out = relu(interp(G)) -> layer2 MFMA -> W3 dot ---------------
// R11's verified pixel loop verbatim; corner frags read from global G (L2-hot).
__global__ __launch_bounds__(256, 4) void t3d_pixel(
    const uint4* __restrict__ G,
    const float* __restrict__ W2, const float* __restrict__ b2,
    const float* __restrict__ W3, const float* __restrict__ b3,
    float* __restrict__ out)
{
    const int tid  = threadIdx.x;
    const int wid  = tid >> 6;
    const int lane = tid & 63;
    const int c = lane & 15, g = lane >> 4;

    const int bid = blockIdx.x;
    const int wg  = (bid & 7) * 256 + (bid >> 3);
    const int RB  = wg >> 4;          // image rows 8RB..8RB+7
    const int cbk = wg & 15;          // 64-pixel column block

    // weight fragments (standard mapping, R11 verbatim)
    FragU aw2[2]; floatx4 bia2[2], w3f[2];
#pragma unroll
    for (int jt = 0; jt < 2; ++jt) {
#pragma unroll
        for (int w = 0; w < 4; ++w)
            aw2[jt].u[w] = pkrtz(W2[(8*g+2*w)*NF + 16*jt + c], W2[(8*g+2*w+1)*NF + 16*jt + c]);
        bia2[jt] = ((const floatx4*)b2)[4*jt + g];
        w3f[jt]  = ((const floatx4*)W3)[4*jt + g];
    }

    const float w0p = (c & 1) ? 0.75f : 0.25f;
    const float m0  = 1.0f - w0p;
    const fp16x2 WA[2] = { sp2(m0  * 0.75f), sp2(m0  * 0.25f) };
    const fp16x2 WB[2] = { sp2(w0p * 0.75f), sp2(w0p * 0.25f) };
    const fp16x2 WC[2] = { sp2(m0  * 0.25f), sp2(m0  * 0.75f) };
    const fp16x2 WD[2] = { sp2(w0p * 0.25f), sp2(w0p * 0.75f) };

    const int y0 = 4 * RB + wid;
    const int y1 = min(y0 + 1, GX - 1);
    const int xbase = 32 * cbk;

    float ss[8];
#pragma unroll
    for (int ct = 0; ct < 4; ++ct) {
        const int x0c = xbase + 8 * ct + (c >> 1);
        const int x1c = min(x0c + 1, GX - 1);
        FragU cT0, cT1, cB0, cB1;
        cT0.u4 = G[g_idx16(y0, x0c, g)];
        cT1.u4 = G[g_idx16(y0, x1c, g)];
        cB0.u4 = G[g_idx16(y1, x0c, g)];
        cB1.u4 = G[g_idx16(y1, x1c, g)];
#pragma unroll
        for (int par = 0; par < 2; ++par) {
            FragU f;
#pragma unroll
            for (int w = 0; w < 4; ++w) {
                fp16x2 t0 = cT0.p[w] * WA[par] + cT1.p[w] * WB[par];
                fp16x2 t1 = cB0.p[w] * WC[par] + cB1.p[w] * WD[par];
                PkU s; s.h = t0 + t1;
                f.u[w] = relu_pk(s.u);           // h1 = relu(interp(G))
            }
            floatx4 e0 = __builtin_amdgcn_mfma_f32_16x16x32_f16(aw2[0].h, f.h, bia2[0], 0, 0, 0);
            floatx4 e1 = __builtin_amdgcn_mfma_f32_16x16x32_f16(aw2[1].h, f.h, bia2[1], 0, 0, 0);
            float t = 0.0f;
#pragma unroll
            for (int r = 0; r < 4; ++r) {
                t = fmaf(fmaxf(e0[r], 0.0f), w3f[0][r], t);
                t = fmaf(fmaxf(e1[r], 0.0f), w3f[1][r], t);
            }
            ss[par * 4 + ct] = t;
        }
    }

    // batched reduction over g-groups (R11 verbatim)
    const bool lo = (lane < 32);
    float tt[4];
#pragma unroll
    for (int k = 0; k < 4; ++k) {
        const float x  = lo ? ss[4 + k] : ss[k];
        const float rv = __shfl_xor(x, 32, 64);
        tt[k] = (lo ? ss[k] : ss[4 + k]) + rv;
    }
    const bool go = (g & 1);
    const float u0 = go ? tt[0] : tt[2];
    const float r0 = __shfl_xor(u0, 16, 64);
    const float fin0 = (go ? tt[2] : tt[0]) + r0;
    const float u1 = go ? tt[1] : tt[3];
    const float r1 = __shfl_xor(u1, 16, 64);
    const float fin1 = (go ? tt[3] : tt[1]) + r1;

    const float b3v = b3[0];
    const int orow = 8 * RB + 2 * wid + (g >> 1);
    const int ocol = 64 * cbk + 32 * (g & 1) + c;
    out[(size_t)orow * XD + ocol]      = fin0 + b3v;
    out[(size_t)orow * XD + ocol + 16] = fin1 + b3v;
}

extern "C" void kernel_launch(void* const* d_in, const int* in_sizes, int n_in,
                              void* d_out, int out_size, void* d_ws, size_t ws_size,
                              hipStream_t stream) {
    // inputs: z, data, W1, b1, W2, b2, W3, b3, x0, y0, x1, y1, lerp_weights
    const float* data = (const float*)d_in[1];
    const float* W1   = (const float*)d_in[2];
    const float* b1   = (const float*)d_in[3];
    const float* W2   = (const float*)d_in[4];
    const float* b2   = (const float*)d_in[5];
    const float* W3   = (const float*)d_in[6];
    const float* b3   = (const float*)d_in[7];
    float* out = (float*)d_out;
    uint4* G  = (uint4*)d_ws;          // 512*512*64 B = 16.8 MB << ws_size

    const int blocks = 2048;
    hipLaunchKernelGGL(t3d_gpass, dim3(blocks), dim3(256), 0, stream,
                       data, W1, b1, G);
    hipLaunchKernelGGL(t3d_pixel, dim3(blocks), dim3(256), 0, stream,
                       (const uint4*)G, W2, b2, W3, b3, out);
}

// Round 14
// 17.494 us; speedup vs baseline: 1.3573x; 1.3573x over previous
//
#include <hip/hip_runtime.h>

#define GX 512
#define NF 32
#define XD 1024

#define CELLB 64                 // f16 cell = 32 feats * 2 B
#define NCELL 33                 // 32 cells + boundary
#define RROWB (NCELL * CELLB)    // 2112 B per staged/G row
#define RAWB  (5 * RROWB)        // 10560 B raw corners (5 grid rows)
#define GOFF  (2 * RAWB)
#define LDSBYTES (2 * RAWB + 8 * RROWB)   // raw dbuf + per-wave G = 38016 B

typedef _Float16 half8 __attribute__((ext_vector_type(8)));
typedef __fp16  fp16x2 __attribute__((ext_vector_type(2)));
typedef float  floatx4 __attribute__((ext_vector_type(4)));

union PkU { fp16x2 h; unsigned u; };
union FragU { half8 h; uint4 u4; fp16x2 p[4]; unsigned u[4]; };

__device__ __forceinline__ unsigned pkrtz(float a, float b) {
    PkU x; x.h = __builtin_amdgcn_cvt_pkrtz(a, b); return x.u;
}
__device__ __forceinline__ fp16x2 sp2(float w) {
    __fp16 h = (__fp16)w; fp16x2 v = {h, h}; return v;
}
__device__ __forceinline__ unsigned relu_pk(unsigned s) {
    unsigned r;
    asm("v_pk_max_f16 %0, %1, 0" : "=v"(r) : "v"(s));
    return r;
}

// R11-verified tile processing (G-compute + pixel loop + reduce + store),
// parameterized by raw-staging base and global column-block index.
__device__ __forceinline__ void process_tile(
    unsigned char* raw, unsigned char* Gw,
    const FragU* aw1, const floatx4* bia1,
    const FragU* aw2, const floatx4* bia2, const floatx4* w3f,
    const fp16x2* WA, const fp16x2* WB, const fp16x2* WC, const fp16x2* WD,
    int wid, int lane, int c, int g, int RB, int cbk, float b3v,
    float* __restrict__ out)
{
    // ---- per-wave G-compute: rows {wid, wid+1} x segs {0-15,16-31,17-32} ---
#pragma unroll
    for (int rl = 0; rl < 2; ++rl) {
        const int rr = wid + rl;
#pragma unroll
        for (int seg = 0; seg < 3; ++seg) {
            const int ct0  = (seg < 2) ? (seg << 4) : 17;
            const int cell = ct0 + c;
            FragU B;
            B.u4 = *(const uint4*)(raw + rr * RROWB + cell * CELLB
                                   + ((g ^ ((cell >> 1) & 3)) << 4));
            floatx4 d0 = __builtin_amdgcn_mfma_f32_16x16x32_f16(aw1[0].h, B.h, bia1[0], 0, 0, 0);
            floatx4 d1 = __builtin_amdgcn_mfma_f32_16x16x32_f16(aw1[1].h, B.h, bia1[1], 0, 0, 0);
            uint2 u0 = { pkrtz(d0[0], d0[1]), pkrtz(d0[2], d0[3]) };
            uint2 u1 = { pkrtz(d1[0], d1[1]), pkrtz(d1[2], d1[3]) };
            const int sg = (cell >> 1) & 3;
            unsigned char* gc = Gw + rl * RROWB + cell * CELLB + ((g & 1) << 3);
            *(uint2*)(gc + ((((g >> 1)    ) ^ sg) << 4)) = u0;   // feats 4g..4g+3
            *(uint2*)(gc + ((((g >> 1) + 2) ^ sg) << 4)) = u1;   // feats 16+4g..
        }
    }

    // ---- pixel loop (same-wave in-order DS; no barrier) --------------------
    unsigned char* Gt = Gw;
    unsigned char* Gm = Gw + RROWB;

    float ss[8];
#pragma unroll
    for (int ct = 0; ct < 4; ++ct) {
        const int o0 = 8 * ct + (c >> 1);
        const int o1 = o0 + 1;                   // boundary cell pre-clamped
        const int a0 = o0 * CELLB + ((g ^ ((o0 >> 1) & 3)) << 4);
        const int a1 = o1 * CELLB + ((g ^ ((o1 >> 1) & 3)) << 4);
        FragU cT0, cT1, cB0, cB1;
        cT0.u4 = *(const uint4*)(Gt + a0);
        cT1.u4 = *(const uint4*)(Gt + a1);
        cB0.u4 = *(const uint4*)(Gm + a0);
        cB1.u4 = *(const uint4*)(Gm + a1);
#pragma unroll
        for (int par = 0; par < 2; ++par) {
            FragU f;
#pragma unroll
            for (int w = 0; w < 4; ++w) {
                fp16x2 t0 = cT0.p[w] * WA[par] + cT1.p[w] * WB[par];
                fp16x2 t1 = cB0.p[w] * WC[par] + cB1.p[w] * WD[par];
                PkU s; s.h = t0 + t1;
                f.u[w] = relu_pk(s.u);           // h1 = relu(interp(G))
            }
            floatx4 e0 = __builtin_amdgcn_mfma_f32_16x16x32_f16(aw2[0].h, f.h, bia2[0], 0, 0, 0);
            floatx4 e1 = __builtin_amdgcn_mfma_f32_16x16x32_f16(aw2[1].h, f.h, bia2[1], 0, 0, 0);
            float t = 0.0f;
#pragma unroll
            for (int r = 0; r < 4; ++r) {
                t = fmaf(fmaxf(e0[r], 0.0f), w3f[0][r], t);
                t = fmaf(fmaxf(e1[r], 0.0f), w3f[1][r], t);
            }
            ss[par * 4 + ct] = t;
        }
    }

    // ---- batched reduction over g-groups (verified pattern) ----------------
    const bool lo = (lane < 32);
    float tt[4];
#pragma unroll
    for (int k = 0; k < 4; ++k) {
        const float x  = lo ? ss[4 + k] : ss[k];
        const float rv = __shfl_xor(x, 32, 64);
        tt[k] = (lo ? ss[k] : ss[4 + k]) + rv;
    }
    const bool go = (g & 1);
    const float u0 = go ? tt[0] : tt[2];
    const float r0 = __shfl_xor(u0, 16, 64);
    const float fin0 = (go ? tt[2] : tt[0]) + r0;
    const float u1 = go ? tt[1] : tt[3];
    const float r1 = __shfl_xor(u1, 16, 64);
    const float fin1 = (go ? tt[3] : tt[1]) + r1;

    const int orow = 8 * RB + 2 * wid + (g >> 1);
    const int ocol = 64 * cbk + 32 * (g & 1) + c;
    out[(size_t)orow * XD + ocol]      = fin0 + b3v;
    out[(size_t)orow * XD + ocol + 16] = fin1 + b3v;
}

// Persistent 2-tile pipeline: 1024 blocks (all co-resident at 4/CU). Block
// processes two adjacent column tiles of the SAME 5 grid rows. Tile1's global
// loads are issued right after barrier0 and consumed (vmcnt wait) only after
// tile0's compute -> HBM latency hidden under compute.
__global__ __launch_bounds__(256, 4) void t3d_main(
    const float* __restrict__ data,
    const float* __restrict__ W1, const float* __restrict__ b1,
    const float* __restrict__ W2, const float* __restrict__ b2,
    const float* __restrict__ W3, const float* __restrict__ b3,
    float* __restrict__ out)
{
    __shared__ uint4 lds4[LDSBYTES / 16];
    unsigned char* raw0 = (unsigned char*)lds4;
    unsigned char* raw1 = raw0 + RAWB;
    unsigned char* Gb   = raw0 + GOFF;

    const int tid  = threadIdx.x;
    const int wid  = tid >> 6;
    const int lane = tid & 63;
    const int c = lane & 15, g = lane >> 4;

    // XCD-chunked bijection over 1024 blocks (128 contiguous pairs per XCD)
    const int obid = blockIdx.x;
    const int p    = (obid & 7) * 128 + (obid >> 3);
    const int RB   = p >> 3;            // row-block: image rows 8RB..8RB+7
    const int cpr  = p & 7;             // column pair
    const int XB0  = 64 * cpr;
    const int XB1  = XB0 + 32;
    const int YB   = 4 * RB;

    const int cl = tid >> 3, fl = tid & 7;   // 8 lanes per cell
    const int y0c = min(YB + 0, GX - 1), y1c = min(YB + 1, GX - 1);
    const int y2c = min(YB + 2, GX - 1), y3c = min(YB + 3, GX - 1);
    const int y4c = min(YB + 4, GX - 1);
    const int rb  = (tid < 40) ? (tid >> 3) : 0;
    const int Lb  = tid & 7;
    const int yb  = min(YB + rb, GX - 1);

#define LOADR(y, XB) (*(const floatx4*)(data + ((size_t)(y) * GX + (XB) + cl) * NF + 4 * fl))
#define LOADB(y, XC) (*(const floatx4*)(data + ((size_t)(y) * GX + (XC)) * NF + 4 * Lb))

    // ---- prefetch tile0 -----------------------------------------------------
    const floatx4 pf0 = LOADR(y0c, XB0), pf1 = LOADR(y1c, XB0), pf2 = LOADR(y2c, XB0),
                  pf3 = LOADR(y3c, XB0), pf4 = LOADR(y4c, XB0);
    const int xb0b = min(XB0 + 32, GX - 1);
    const floatx4 pfb = LOADB(yb, xb0b);

    // ---- weight fragments (R11 verbatim) ------------------------------------
    FragU aw1[2], aw2[2]; floatx4 bia1[2], bia2[2], w3f[2];
#pragma unroll
    for (int jt = 0; jt < 2; ++jt) {
#pragma unroll
        for (int w = 0; w < 4; ++w) {
            aw1[jt].u[w] = pkrtz(W1[(8*g+2*w)*NF + 16*jt + c], W1[(8*g+2*w+1)*NF + 16*jt + c]);
            aw2[jt].u[w] = pkrtz(W2[(8*g+2*w)*NF + 16*jt + c], W2[(8*g+2*w+1)*NF + 16*jt + c]);
        }
        bia1[jt] = ((const floatx4*)b1)[4*jt + g];
        bia2[jt] = ((const floatx4*)b2)[4*jt + g];
        w3f[jt]  = ((const floatx4*)W3)[4*jt + g];
    }
    const float b3v = b3[0];

    const int wadr = cl * CELLB + (((fl >> 1) ^ ((cl >> 1) & 3)) << 4) + ((fl & 1) << 3);
    const int badr = 32 * CELLB + ((Lb >> 1) << 4) + ((Lb & 1) << 3);

#define STW(base, rr, v) { uint2 u = { pkrtz((v)[0], (v)[1]), pkrtz((v)[2], (v)[3]) }; \
                           *(uint2*)((base) + (rr) * RROWB + wadr) = u; }
#define STB(base, v)     { uint2 u = { pkrtz((v)[0], (v)[1]), pkrtz((v)[2], (v)[3]) }; \
                           *(uint2*)((base) + rb * RROWB + badr) = u; }

    // ---- stage buf0 ---------------------------------------------------------
    STW(raw0, 0, pf0) STW(raw0, 1, pf1) STW(raw0, 2, pf2) STW(raw0, 3, pf3) STW(raw0, 4, pf4)
    if (tid < 40) STB(raw0, pfb)
    __syncthreads();

    // ---- issue tile1 prefetch (consumed after tile0 compute) ---------------
    const floatx4 qf0 = LOADR(y0c, XB1), qf1 = LOADR(y1c, XB1), qf2 = LOADR(y2c, XB1),
                  qf3 = LOADR(y3c, XB1), qf4 = LOADR(y4c, XB1);
    const int xb1b = min(XB1 + 32, GX - 1);
    const floatx4 qfb = LOADB(yb, xb1b);

    // ---- interp weights (exact quarter fractions) ---------------------------
    const float w0p = (c & 1) ? 0.75f : 0.25f;
    const float m0  = 1.0f - w0p;
    const fp16x2 WA[2] = { sp2(m0  * 0.75f), sp2(m0  * 0.25f) };
    const fp16x2 WB[2] = { sp2(w0p * 0.75f), sp2(w0p * 0.25f) };
    const fp16x2 WC[2] = { sp2(m0  * 0.25f), sp2(m0  * 0.75f) };
    const fp16x2 WD[2] = { sp2(w0p * 0.25f), sp2(w0p * 0.75f) };

    unsigned char* Gw = Gb + wid * (2 * RROWB);

    // ---- tile 0 -------------------------------------------------------------
    process_tile(raw0, Gw, aw1, bia1, aw2, bia2, w3f, WA, WB, WC, WD,
                 wid, lane, c, g, RB, 2 * cpr, b3v, out);

    // ---- stage buf1 (vmcnt waits here, after tile0 compute) ----------------
    STW(raw1, 0, qf0) STW(raw1, 1, qf1) STW(raw1, 2, qf2) STW(raw1, 3, qf3) STW(raw1, 4, qf4)
    if (tid < 40) STB(raw1, qfb)
    __syncthreads();

    // ---- tile 1 -------------------------------------------------------------
    process_tile(raw1, Gw, aw1, bia1, aw2, bia2, w3f, WA, WB, WC, WD,
                 wid, lane, c, g, RB, 2 * cpr + 1, b3v, out);

#undef LOADR
#undef LOADB
#undef STW
#undef STB
}

extern "C" void kernel_launch(void* const* d_in, const int* in_sizes, int n_in,
                              void* d_out, int out_size, void* d_ws, size_t ws_size,
                              hipStream_t stream) {
    // inputs: z, data, W1, b1, W2, b2, W3, b3, x0, y0, x1, y1, lerp_weights
    const float* data = (const float*)d_in[1];
    const float* W1   = (const float*)d_in[2];
    const float* b1   = (const float*)d_in[3];
    const float* W2   = (const float*)d_in[4];
    const float* b2   = (const float*)d_in[5];
    const float* W3   = (const float*)d_in[6];
    const float* b3   = (const float*)d_in[7];
    float* out = (float*)d_out;
    (void)d_ws; (void)ws_size;

    hipLaunchKernelGGL(t3d_main, dim3(1024), dim3(256), 0, stream,
                       data, W1, b1, W2, b2, W3, b3, out);
}

// Round 15
// 16.974 us; speedup vs baseline: 1.3988x; 1.0306x over previous
//
#include <hip/hip_runtime.h>

#define GX 512
#define NF 32
#define XD 1024

#define CELLB 64                 // f16 cell = 32 feats * 2 B
#define NCELL 33                 // 32 cells + boundary
#define RROWB (NCELL * CELLB)    // 2112 B per staged row
#define RAWB  (5 * RROWB)        // 10560 B raw corners (5 grid rows) -- ONLY LDS

typedef _Float16 half8 __attribute__((ext_vector_type(8)));
typedef __fp16  fp16x2 __attribute__((ext_vector_type(2)));
typedef float  floatx4 __attribute__((ext_vector_type(4)));

union PkU { fp16x2 h; unsigned u; };
union FragU { half8 h; uint4 u4; fp16x2 p[4]; unsigned u[4]; };

__device__ __forceinline__ unsigned pkrtz(float a, float b) {
    PkU x; x.h = __builtin_amdgcn_cvt_pkrtz(a, b); return x.u;
}
__device__ __forceinline__ unsigned relu_pk(unsigned s) {
    unsigned r;
    asm("v_pk_max_f16 %0, %1, 0" : "=v"(r) : "v"(s));
    return r;
}

// G-in-registers: pixel tiles are SAME-PARITY columns (col = 32s + 2c + tp), so
// lane c's x0-cell = 16s+c = the G-MFMA's own output column; x1 comes from a
// second shifted G-MFMA (cell+1). Layer-2 A-frag k-slots are permuted
// pi(8g+j) = {4g+j, 16+4g+(j-4)} so G's natural C/D quads (feats 4g+r,16+4g+r),
// after f32 interp + relu/pack, ARE the layer-2 B-frag. No G LDS round-trip:
// DS per wave = 6 staging writes + 8 b128 reads (was ~34 ops).
__global__ __launch_bounds__(256, 4) void t3d_main(
    const float* __restrict__ data,
    const float* __restrict__ W1, const float* __restrict__ b1,
    const float* __restrict__ W2, const float* __restrict__ b2,
    const float* __restrict__ W3, const float* __restrict__ b3,
    float* __restrict__ out)
{
    __shared__ uint4 lds4[RAWB / 16];
    unsigned char* raw = (unsigned char*)lds4;

    const int tid  = threadIdx.x;
    const int wid  = tid >> 6;
    const int lane = tid & 63;
    const int c = lane & 15, g = lane >> 4;

    // XCD swizzle: 2048 wgs, 8 XCDs, 256 contiguous per XCD (bijective)
    const int bid = blockIdx.x;
    const int wg  = (bid & 7) * 256 + (bid >> 3);
    const int RB  = wg >> 4;          // row-block: image rows 8RB..8RB+7
    const int cbk = wg & 15;          // 64-pixel column block
    const int XB  = 32 * cbk;         // first grid cell
    const int YB  = 4 * RB;           // first grid row

    // ---- cooperative staging: 5 grid rows x 33 cells, f32 -> f16 (R11) -----
    const int cl = tid >> 3, fl = tid & 7;   // 8 lanes per cell, 32 cells
#pragma unroll
    for (int rr = 0; rr < 5; ++rr) {
        const int y = min(YB + rr, GX - 1);
        const float4 v = *(const float4*)(data + (size_t)y * (GX * NF) + (XB + cl) * NF + 4 * fl);
        uint2 u = { pkrtz(v.x, v.y), pkrtz(v.z, v.w) };
        *(uint2*)(raw + rr * RROWB + cl * CELLB
                  + (((fl >> 1) ^ ((cl >> 1) & 3)) << 4) + ((fl & 1) << 3)) = u;
    }
    if (tid < 40) {   // boundary cell 32 (clamped at grid edge)
        const int rr = tid >> 3, L = tid & 7;
        const int y = min(YB + rr, GX - 1);
        const int col = min(XB + 32, GX - 1);
        const float4 v = *(const float4*)(data + (size_t)y * (GX * NF) + col * NF + 4 * L);
        uint2 u = { pkrtz(v.x, v.y), pkrtz(v.z, v.w) };
        *(uint2*)(raw + rr * RROWB + 32 * CELLB + ((L >> 1) << 4) + ((L & 1) << 3)) = u;
    }

    // ---- weight fragments ---------------------------------------------------
    // aw1: standard k-mapping (R11 verbatim). aw2: PI-PERMUTED k-slots.
    FragU aw1[2], aw2[2]; floatx4 bia1[2], bia2[2], w3f[2];
#pragma unroll
    for (int jt = 0; jt < 2; ++jt) {
#pragma unroll
        for (int w = 0; w < 4; ++w)
            aw1[jt].u[w] = pkrtz(W1[(8*g+2*w)*NF + 16*jt + c], W1[(8*g+2*w+1)*NF + 16*jt + c]);
        // pi(8g+j): j=0..3 -> rows 4g+j ; j=4..7 -> rows 16+4g+(j-4)
        aw2[jt].u[0] = pkrtz(W2[(4*g+0)*NF + 16*jt + c],  W2[(4*g+1)*NF + 16*jt + c]);
        aw2[jt].u[1] = pkrtz(W2[(4*g+2)*NF + 16*jt + c],  W2[(4*g+3)*NF + 16*jt + c]);
        aw2[jt].u[2] = pkrtz(W2[(16+4*g+0)*NF + 16*jt + c], W2[(16+4*g+1)*NF + 16*jt + c]);
        aw2[jt].u[3] = pkrtz(W2[(16+4*g+2)*NF + 16*jt + c], W2[(16+4*g+3)*NF + 16*jt + c]);
        bia1[jt] = ((const floatx4*)b1)[4*jt + g];
        bia2[jt] = ((const floatx4*)b2)[4*jt + g];
        w3f[jt]  = ((const floatx4*)W3)[4*jt + g];
    }

    __syncthreads();   // staging is cross-wave; only barrier

#define RD(rr, cell) (*(const uint4*)(raw + (rr) * RROWB + (cell) * CELLB \
                      + ((g ^ (((cell) >> 1) & 3)) << 4)))

    float ss[8];
    // wave = image rows {2wid, 2wid+1}; grid rows wid (T), wid+1 (B)
#pragma unroll
    for (int s = 0; s < 2; ++s) {
        const int c0 = 16 * s + c;
        FragU Bat, Bst, Bab, Bsb;
        Bat.u4 = RD(wid,     c0);      // aligned, top row
        Bst.u4 = RD(wid,     c0 + 1);  // shifted (x1), top
        Bab.u4 = RD(wid + 1, c0);      // aligned, bottom
        Bsb.u4 = RD(wid + 1, c0 + 1);  // shifted, bottom
        // 8 G-MFMAs: quads = feats {4g+r} (jt0) and {16+4g+r} (jt1) of cell col
        floatx4 GTA0 = __builtin_amdgcn_mfma_f32_16x16x32_f16(aw1[0].h, Bat.h, bia1[0], 0, 0, 0);
        floatx4 GTA1 = __builtin_amdgcn_mfma_f32_16x16x32_f16(aw1[1].h, Bat.h, bia1[1], 0, 0, 0);
        floatx4 GTS0 = __builtin_amdgcn_mfma_f32_16x16x32_f16(aw1[0].h, Bst.h, bia1[0], 0, 0, 0);
        floatx4 GTS1 = __builtin_amdgcn_mfma_f32_16x16x32_f16(aw1[1].h, Bst.h, bia1[1], 0, 0, 0);
        floatx4 GBA0 = __builtin_amdgcn_mfma_f32_16x16x32_f16(aw1[0].h, Bab.h, bia1[0], 0, 0, 0);
        floatx4 GBA1 = __builtin_amdgcn_mfma_f32_16x16x32_f16(aw1[1].h, Bab.h, bia1[1], 0, 0, 0);
        floatx4 GBS0 = __builtin_amdgcn_mfma_f32_16x16x32_f16(aw1[0].h, Bsb.h, bia1[0], 0, 0, 0);
        floatx4 GBS1 = __builtin_amdgcn_mfma_f32_16x16x32_f16(aw1[1].h, Bsb.h, bia1[1], 0, 0, 0);

#pragma unroll
        for (int rr = 0; rr < 2; ++rr) {       // image-row parity (y lerp)
#pragma unroll
            for (int tp = 0; tp < 2; ++tp) {   // column parity (x lerp)
                const float w0v = tp ? 0.75f : 0.25f;
                const float w1v = rr ? 0.75f : 0.25f;
                const float wA = (1.0f - w0v) * (1.0f - w1v);
                const float wB = w0v * (1.0f - w1v);
                const float wC = (1.0f - w0v) * w1v;
                const float wD = w0v * w1v;
                // f32 interp of G quads (single rounding into f16 B-frag)
                floatx4 d0 = wA * GTA0 + wB * GTS0 + wC * GBA0 + wD * GBS0;
                floatx4 d1 = wA * GTA1 + wB * GTS1 + wC * GBA1 + wD * GBS1;
                FragU f;
                f.u[0] = relu_pk(pkrtz(d0[0], d0[1]));   // k-slots 0,1 = feats 4g,4g+1
                f.u[1] = relu_pk(pkrtz(d0[2], d0[3]));
                f.u[2] = relu_pk(pkrtz(d1[0], d1[1]));   // k-slots 4,5 = feats 16+4g,..
                f.u[3] = relu_pk(pkrtz(d1[2], d1[3]));
                floatx4 e0 = __builtin_amdgcn_mfma_f32_16x16x32_f16(aw2[0].h, f.h, bia2[0], 0, 0, 0);
                floatx4 e1 = __builtin_amdgcn_mfma_f32_16x16x32_f16(aw2[1].h, f.h, bia2[1], 0, 0, 0);
                float t = 0.0f;
#pragma unroll
                for (int r = 0; r < 4; ++r) {
                    t = fmaf(fmaxf(e0[r], 0.0f), w3f[0][r], t);
                    t = fmaf(fmaxf(e1[r], 0.0f), w3f[1][r], t);
                }
                ss[(rr << 2) + (s << 1) + tp] = t;
            }
        }
    }
#undef RD

    // ---- batched reduction over g-groups (verified pattern) ----------------
    const bool lo = (lane < 32);
    float tt[4];
#pragma unroll
    for (int k = 0; k < 4; ++k) {
        const float x  = lo ? ss[4 + k] : ss[k];
        const float rv = __shfl_xor(x, 32, 64);
        tt[k] = (lo ? ss[k] : ss[4 + k]) + rv;
    }
    const bool go = (g & 1);
    const float u0 = go ? tt[0] : tt[2];
    const float r0 = __shfl_xor(u0, 16, 64);
    const float fin0 = (go ? tt[2] : tt[0]) + r0;
    const float u1 = go ? tt[1] : tt[3];
    const float r1 = __shfl_xor(u1, 16, 64);
    const float fin1 = (go ? tt[3] : tt[1]) + r1;

    // lane (g,c): slots (2g,2g+1) = (rr=g>>1, s=g&1, tp=0/1)
    // -> row 2wid+(g>>1), cols 32(g&1)+2c, +2c+1  (contiguous float2)
    const float b3v = b3[0];
    const int orow = 8 * RB + 2 * wid + (g >> 1);
    const int ocol = 64 * cbk + 32 * (g & 1) + 2 * c;
    float2 o2 = { fin0 + b3v, fin1 + b3v };
    *(float2*)(out + (size_t)orow * XD + ocol) = o2;
}

extern "C" void kernel_launch(void* const* d_in, const int* in_sizes, int n_in,
                              void* d_out, int out_size, void* d_ws, size_t ws_size,
                              hipStream_t stream) {
    // inputs: z, data, W1, b1, W2, b2, W3, b3, x0, y0, x1, y1, lerp_weights
    const float* data = (const float*)d_in[1];
    const float* W1   = (const float*)d_in[2];
    const float* b1   = (const float*)d_in[3];
    const float* W2   = (const float*)d_in[4];
    const float* b2   = (const float*)d_in[5];
    const float* W3   = (const float*)d_in[6];
    const float* b3   = (const float*)d_in[7];
    float* out = (float*)d_out;
    (void)d_ws; (void)ws_size;

    const int blocks = 2048;   // 128 row-blocks x 16 col-blocks
    hipLaunchKernelGGL(t3d_main, dim3(blocks), dim3(256), 0, stream,
                       data, W1, b1, W2, b2, W3, b3, out);
}